// Round 2
// baseline (283.291 us; speedup 1.0000x reference)
//
#include <hip/hip_runtime.h>

#define B_ 2
#define C_ 128
#define H_ 96
#define W_ 96
#define HEADS_ 4
#define HD_ 32
#define M_ 16
#define WIN_ 7
#define PAD_ 3
#define N_ (H_*W_)              // 9216
#define HP_ (H_+2*PAD_)         // 102
#define KW_ (WIN_*WIN_)         // 49
#define TILE_ 16
#define HALO_ (TILE_+WIN_-1)    // 22
#define NHALO_ (HALO_*HALO_)    // 484

static __device__ __forceinline__ unsigned int f2bf(float f) {
    unsigned int u = __float_as_uint(f);
    u = (u + 0x7fffu + ((u >> 16) & 1u)) >> 16;   // RNE to bf16
    return u & 0xffffu;
}
static __device__ __forceinline__ float bf_lo(unsigned int u){ return __uint_as_float(u << 16); }
static __device__ __forceinline__ float bf_hi(unsigned int u){ return __uint_as_float(u & 0xffff0000u); }

// inline function, not a macro: macro params named w/x/y/z collide with
// float4 member access under preprocessor substitution.
static __device__ __forceinline__ void fma4(float4& acc, float s, const float4& v) {
    acc.x = fmaf(s, v.x, acc.x);
    acc.y = fmaf(s, v.y, acc.y);
    acc.z = fmaf(s, v.z, acc.z);
    acc.w = fmaf(s, v.w, acc.w);
}

// ---------------------------------------------------------------------------
// Kernel 1: fill padded borders of Kp/Vp with bias (proj of zero input),
// and build phiT: [B][102][102][16] fp32, border = 1.0
// ---------------------------------------------------------------------------
__global__ __launch_bounds__(256) void pad_fill(
    const float* __restrict__ phi, const float* __restrict__ bk, const float* __restrict__ bv,
    float* __restrict__ Kp, float* __restrict__ Vp, float* __restrict__ PhiT)
{
    int idx = blockIdx.x * 256 + threadIdx.x;
    const int tot = B_*HP_*HP_;
    if (idx >= tot) return;
    int b  = idx / (HP_*HP_);
    int pp = idx % (HP_*HP_);
    int py = pp / HP_, px = pp % HP_;
    bool interior = (py >= PAD_ && py < H_+PAD_ && px >= PAD_ && px < W_+PAD_);
    if (!interior) {
        size_t base = ((size_t)b*HP_*HP_ + pp) * C_;
        #pragma unroll 8
        for (int c4 = 0; c4 < 32; ++c4) {
            ((float4*)(Kp + base))[c4] = ((const float4*)bk)[c4];
            ((float4*)(Vp + base))[c4] = ((const float4*)bv)[c4];
        }
    }
    size_t pb = ((size_t)b*HP_*HP_ + pp) * M_;
    if (interior) {
        int y = py - PAD_, xx = px - PAD_;
        #pragma unroll
        for (int m = 0; m < M_; ++m)
            PhiT[pb + m] = phi[((size_t)b*M_ + m)*N_ + y*W_ + xx];
    } else {
        #pragma unroll
        for (int m = 0; m < M_; ++m) PhiT[pb + m] = 1.0f;
    }
}

// ---------------------------------------------------------------------------
// Kernel 2: fused Q/K/V projection (fp32 GEMV tiles).
// Block: 256 threads, 32 pixels. LDS: xT [ci][pix] 16KB + W half-tile 32KB.
// Thread register tile: 4 co x 4 pix.
// Q written [B][N][C]; K/V written into padded [B][102][102][C] interior.
// ---------------------------------------------------------------------------
__global__ __launch_bounds__(256, 3) void qkv_proj(
    const float* __restrict__ x,
    const float* __restrict__ Wq, const float* __restrict__ bq,
    const float* __restrict__ Wk, const float* __restrict__ bk,
    const float* __restrict__ Wv, const float* __restrict__ bv,
    float* __restrict__ Qp, float* __restrict__ Kp, float* __restrict__ Vp)
{
    __shared__ float4 ldsW4[64*32];   // 64 ci rows x 128 co  (32 KB)
    __shared__ float4 ldsX4[128*8];   // [ci][pix] 128 x 32   (16 KB)

    const int t   = threadIdx.x;
    const int blk = blockIdx.x;                 // B_*(N_/32) = 576
    const int b   = blk / (N_/32);
    const int n0  = (blk % (N_/32)) * 32;

    // stage x tile transposed: ldsX[ci][pix]
    for (int idx = t; idx < 128*32; idx += 256) {
        int pix = idx & 31, ci = idx >> 5;
        ((float*)ldsX4)[ci*32 + pix] = x[((size_t)b*C_ + ci)*N_ + n0 + pix];
    }

    const float* Ws[3] = {Wq, Wk, Wv};
    const float* bs[3] = {bq, bk, bv};

    const int co_g  = t & 31;   // co = co_g*4 .. +3
    const int pix_g = t >> 5;   // pix = pix_g*4 .. +3

    for (int pj = 0; pj < 3; ++pj) {
        float4 bias = *(const float4*)(bs[pj] + co_g*4);
        float4 acc0 = bias, acc1 = bias, acc2 = bias, acc3 = bias;
        for (int half = 0; half < 2; ++half) {
            __syncthreads();   // protect previous ldsW readers (and first x stage)
            const float4* wsrc = (const float4*)(Ws[pj] + (size_t)half*64*C_);
            for (int idx = t; idx < 64*32; idx += 256) ldsW4[idx] = wsrc[idx];
            __syncthreads();
            #pragma unroll 8
            for (int ci = 0; ci < 64; ++ci) {
                float4 xv = ldsX4[(half*64 + ci)*8 + pix_g];
                float4 wv = ldsW4[ci*32 + co_g];
                fma4(acc0, xv.x, wv);
                fma4(acc1, xv.y, wv);
                fma4(acc2, xv.z, wv);
                fma4(acc3, xv.w, wv);
            }
        }
        float4 accs[4] = {acc0, acc1, acc2, acc3};
        #pragma unroll
        for (int p = 0; p < 4; ++p) {
            int n = n0 + pix_g*4 + p;
            if (pj == 0) {
                *(float4*)(Qp + ((size_t)b*N_ + n)*C_ + co_g*4) = accs[p];
            } else {
                int y = n / W_, xx = n % W_;
                size_t off = (((size_t)b*HP_ + (y+PAD_))*HP_ + (xx+PAD_))*C_ + co_g*4;
                float* dst = (pj == 1) ? Kp : Vp;
                *(float4*)(dst + off) = accs[p];
            }
        }
    }
}

// ---------------------------------------------------------------------------
// Kernel 3: local attention. One block per (b, head, 16x16 tile).
// K/V halo (22x22 rows of 32 ch) staged in LDS as bf16, XOR-swizzled uint4.
// Geo term from fp32 PhiT via global (L1-resident halo). AO may alias Qp.
// ---------------------------------------------------------------------------
__global__ __launch_bounds__(256, 2) void attn(
    const float* __restrict__ Qp, const float* __restrict__ Kp, const float* __restrict__ Vp,
    const float* __restrict__ PhiT, const float* __restrict__ log_alpha,
    const float* __restrict__ beta, float* __restrict__ AO)
{
    __shared__ uint4 kl[NHALO_*4];   // 484 rows x 4 slots (8 bf16 each) = 30976 B
    __shared__ uint4 vl[NHALO_*4];

    const int t  = threadIdx.x;
    const int h  = blockIdx.y;
    const int b  = blockIdx.z;
    const int y0 = ((int)blockIdx.x / 6) * TILE_;
    const int x0 = ((int)blockIdx.x % 6) * TILE_;

    // stage halo K/V -> bf16 LDS
    for (int idx = t; idx < NHALO_*4; idx += 256) {
        int hp = idx >> 2, s = idx & 3;
        int hy = hp / HALO_, hx = hp % HALO_;
        size_t gb = (((size_t)b*HP_ + (y0+hy))*HP_ + (x0+hx))*C_ + h*HD_ + s*8;
        float4 ka = *(const float4*)(Kp + gb);
        float4 kb = *(const float4*)(Kp + gb + 4);
        float4 va = *(const float4*)(Vp + gb);
        float4 vb = *(const float4*)(Vp + gb + 4);
        uint4 ku, vu;
        ku.x = f2bf(ka.x) | (f2bf(ka.y) << 16);
        ku.y = f2bf(ka.z) | (f2bf(ka.w) << 16);
        ku.z = f2bf(kb.x) | (f2bf(kb.y) << 16);
        ku.w = f2bf(kb.z) | (f2bf(kb.w) << 16);
        vu.x = f2bf(va.x) | (f2bf(va.y) << 16);
        vu.y = f2bf(va.z) | (f2bf(va.w) << 16);
        vu.z = f2bf(vb.x) | (f2bf(vb.y) << 16);
        vu.w = f2bf(vb.z) | (f2bf(vb.w) << 16);
        int slot = (hp << 2) + (s ^ (hp & 3));
        kl[slot] = ku; vl[slot] = vu;
    }
    __syncthreads();

    const int qy = t >> 4, qx = t & 15;
    const int yq = y0 + qy, xq = x0 + qx;
    const int n  = yq*W_ + xq;

    float4 q4[8];
    const float* qptr = Qp + ((size_t)b*N_ + n)*C_ + h*HD_;
    #pragma unroll
    for (int d = 0; d < 8; ++d) q4[d] = ((const float4*)qptr)[d];

    float pc[16];
    const float* pcp = PhiT + (((size_t)b*HP_ + (yq+PAD_))*HP_ + (xq+PAD_))*M_;
    #pragma unroll
    for (int m = 0; m < 16; ++m) pc[m] = pcp[m];

    const float alpha = __expf(log_alpha[0]);
    const float scale = 0.17677669529663687f;            // 1/sqrt(32) = HD^-0.5
    const float gcoef = -beta[h] * alpha * 0.17677669529663687f; // beta * (-alpha/sqrt(2M))

    float l[KW_];
    float mx = -1e30f;
    #pragma unroll
    for (int i = 0; i < WIN_; ++i) {
        #pragma unroll
        for (int j = 0; j < WIN_; ++j) {
            int hp = (qy+i)*HALO_ + (qx+j);
            float4 acc = make_float4(0.f,0.f,0.f,0.f);
            #pragma unroll
            for (int s = 0; s < 4; ++s) {
                uint4 kw = kl[(hp << 2) + (s ^ (hp & 3))];
                float4 qa = q4[s*2], qb = q4[s*2+1];
                acc.x = fmaf(qa.x, bf_lo(kw.x), acc.x);
                acc.y = fmaf(qa.y, bf_hi(kw.x), acc.y);
                acc.z = fmaf(qa.z, bf_lo(kw.y), acc.z);
                acc.w = fmaf(qa.w, bf_hi(kw.y), acc.w);
                acc.x = fmaf(qb.x, bf_lo(kw.z), acc.x);
                acc.y = fmaf(qb.y, bf_hi(kw.z), acc.y);
                acc.z = fmaf(qb.z, bf_lo(kw.w), acc.z);
                acc.w = fmaf(qb.w, bf_hi(kw.w), acc.w);
            }
            float dot = (acc.x + acc.y) + (acc.z + acc.w);
            const float* pn = PhiT + (((size_t)b*HP_ + (y0+qy+i))*HP_ + (x0+qx+j))*M_;
            float4 g = make_float4(0.f,0.f,0.f,0.f);
            #pragma unroll
            for (int m4 = 0; m4 < 4; ++m4) {
                float4 pv = ((const float4*)pn)[m4];
                float d0 = pc[m4*4+0]-pv.x, d1 = pc[m4*4+1]-pv.y;
                float d2 = pc[m4*4+2]-pv.z, d3 = pc[m4*4+3]-pv.w;
                g.x = fmaf(d0,d0,g.x); g.y = fmaf(d1,d1,g.y);
                g.z = fmaf(d2,d2,g.z); g.w = fmaf(d3,d3,g.w);
            }
            float dsq = (g.x + g.y) + (g.z + g.w);
            float lg = fmaf(dot, scale, gcoef*dsq);
            l[i*WIN_+j] = lg;
            mx = fmaxf(mx, lg);
        }
    }
    float ssum = 0.f;
    #pragma unroll
    for (int kk = 0; kk < KW_; ++kk) { float e = __expf(l[kk]-mx); l[kk] = e; ssum += e; }
    float inv = 1.0f / ssum;

    float4 o[8];
    #pragma unroll
    for (int d = 0; d < 8; ++d) o[d] = make_float4(0.f,0.f,0.f,0.f);
    #pragma unroll
    for (int i = 0; i < WIN_; ++i) {
        #pragma unroll
        for (int j = 0; j < WIN_; ++j) {
            int hp = (qy+i)*HALO_ + (qx+j);
            float w = l[i*WIN_+j];
            #pragma unroll
            for (int s = 0; s < 4; ++s) {
                uint4 vw = vl[(hp << 2) + (s ^ (hp & 3))];
                o[s*2].x   = fmaf(w, bf_lo(vw.x), o[s*2].x);
                o[s*2].y   = fmaf(w, bf_hi(vw.x), o[s*2].y);
                o[s*2].z   = fmaf(w, bf_lo(vw.y), o[s*2].z);
                o[s*2].w   = fmaf(w, bf_hi(vw.y), o[s*2].w);
                o[s*2+1].x = fmaf(w, bf_lo(vw.z), o[s*2+1].x);
                o[s*2+1].y = fmaf(w, bf_hi(vw.z), o[s*2+1].y);
                o[s*2+1].z = fmaf(w, bf_lo(vw.w), o[s*2+1].z);
                o[s*2+1].w = fmaf(w, bf_hi(vw.w), o[s*2+1].w);
            }
        }
    }
    float* aop = AO + ((size_t)b*N_ + n)*C_ + h*HD_;
    #pragma unroll
    for (int d = 0; d < 8; ++d) {
        float4 ov = o[d];
        ov.x *= inv; ov.y *= inv; ov.z *= inv; ov.w *= inv;
        ((float4*)aop)[d] = ov;
    }
}

// ---------------------------------------------------------------------------
// Kernel 4: output projection. 64 pixels/block; AO tile in swizzled LDS;
// Wo broadcast from L2. Coalesced [B][C][N] stores.
// ---------------------------------------------------------------------------
__global__ __launch_bounds__(256, 4) void out_proj(
    const float* __restrict__ AO, const float* __restrict__ Wo,
    const float* __restrict__ bo, float* __restrict__ out)
{
    __shared__ float4 aos[64*32];   // 32 KB
    const int t   = threadIdx.x;
    const int blk = blockIdx.x;                 // B_*(N_/64) = 288
    const int b   = blk / (N_/64);
    const int n0  = (blk % (N_/64)) * 64;

    for (int idx = t; idx < 64*32; idx += 256) {
        int nl = idx >> 5, c4 = idx & 31;
        aos[nl*32 + (c4 ^ (nl & 31))] =
            ((const float4*)(AO + ((size_t)b*N_ + n0 + nl)*C_))[c4];
    }
    __syncthreads();

    const int nl = t & 63, cg = t >> 6;
    const int n  = n0 + nl;
    #pragma unroll
    for (int c8 = 0; c8 < 8; ++c8) {
        int co = cg*32 + c8*4;
        float4 acc = *(const float4*)(bo + co);
        #pragma unroll 8
        for (int c4 = 0; c4 < 32; ++c4) {
            float4 xv = aos[nl*32 + (c4 ^ (nl & 31))];
            float4 w0 = *(const float4*)(Wo + (size_t)(c4*4+0)*C_ + co);
            float4 w1 = *(const float4*)(Wo + (size_t)(c4*4+1)*C_ + co);
            float4 w2 = *(const float4*)(Wo + (size_t)(c4*4+2)*C_ + co);
            float4 w3 = *(const float4*)(Wo + (size_t)(c4*4+3)*C_ + co);
            fma4(acc, xv.x, w0);
            fma4(acc, xv.y, w1);
            fma4(acc, xv.z, w2);
            fma4(acc, xv.w, w3);
        }
        out[((size_t)b*C_ + co+0)*N_ + n] = acc.x;
        out[((size_t)b*C_ + co+1)*N_ + n] = acc.y;
        out[((size_t)b*C_ + co+2)*N_ + n] = acc.z;
        out[((size_t)b*C_ + co+3)*N_ + n] = acc.w;
    }
}

// ---------------------------------------------------------------------------
extern "C" void kernel_launch(void* const* d_in, const int* in_sizes, int n_in,
                              void* d_out, int out_size, void* d_ws, size_t ws_size,
                              hipStream_t stream)
{
    const float* x    = (const float*)d_in[0];
    const float* phi  = (const float*)d_in[1];
    const float* Wq   = (const float*)d_in[2];
    const float* bq   = (const float*)d_in[3];
    const float* Wk   = (const float*)d_in[4];
    const float* bk   = (const float*)d_in[5];
    const float* Wv   = (const float*)d_in[6];
    const float* bv   = (const float*)d_in[7];
    const float* Wo   = (const float*)d_in[8];
    const float* bo   = (const float*)d_in[9];
    const float* la   = (const float*)d_in[10];
    const float* beta = (const float*)d_in[11];
    float* out = (float*)d_out;

    // workspace layout (floats). AO aliases Qp: each attn thread fully reads
    // its q slice into registers before writing the identical AO slice.
    float* ws   = (float*)d_ws;
    float* Qp   = ws;                                   // B*N*C      = 2,359,296
    float* Kp   = Qp + (size_t)B_*N_*C_;                // B*102^2*C  = 2,663,424
    float* Vp   = Kp + (size_t)B_*HP_*HP_*C_;           // B*102^2*C  = 2,663,424
    float* PhiT = Vp + (size_t)B_*HP_*HP_*C_;           // B*102^2*M  =   332,928
    float* AO   = Qp;                                   // aliased

    pad_fill<<<dim3((B_*HP_*HP_ + 255)/256), dim3(256), 0, stream>>>(phi, bk, bv, Kp, Vp, PhiT);
    qkv_proj<<<dim3(B_*(N_/32)), dim3(256), 0, stream>>>(x, Wq, bq, Wk, bk, Wv, bv, Qp, Kp, Vp);
    attn<<<dim3(36, HEADS_, B_), dim3(256), 0, stream>>>(Qp, Kp, Vp, PhiT, la, beta, AO);
    out_proj<<<dim3(B_*(N_/64)), dim3(256), 0, stream>>>(AO, Wo, bo, out);
}

// Round 3
// 192.472 us; speedup vs baseline: 1.4719x; 1.4719x over previous
//
#include <hip/hip_runtime.h>

#define B_ 2
#define C_ 128
#define H_ 96
#define W_ 96
#define HEADS_ 4
#define HD_ 32
#define M_ 16
#define WIN_ 7
#define PAD_ 3
#define N_ (H_*W_)              // 9216
#define HP_ (H_+2*PAD_)         // 102
#define KW_ (WIN_*WIN_)         // 49
#define TILE_ 8                 // attn tile is 8x8 pixels
#define HALO_ (TILE_+WIN_-1)    // 14
#define NHALO_ (HALO_*HALO_)    // 196

static __device__ __forceinline__ unsigned int f2bf(float f) {
    unsigned int u = __float_as_uint(f);
    u = (u + 0x7fffu + ((u >> 16) & 1u)) >> 16;   // RNE to bf16
    return u & 0xffffu;
}
static __device__ __forceinline__ float bf_lo(unsigned int u){ return __uint_as_float(u << 16); }
static __device__ __forceinline__ float bf_hi(unsigned int u){ return __uint_as_float(u & 0xffff0000u); }

// inline function, not a macro: macro params named w/x/y/z collide with
// float4 member access under preprocessor substitution.
static __device__ __forceinline__ void fma4(float4& acc, float s, const float4& v) {
    acc.x = fmaf(s, v.x, acc.x);
    acc.y = fmaf(s, v.y, acc.y);
    acc.z = fmaf(s, v.z, acc.z);
    acc.w = fmaf(s, v.w, acc.w);
}

// ---------------------------------------------------------------------------
// Kernel 1: fill padded borders of Kp/Vp with bias (proj of zero input),
// and build phiT: [B][102][102][16] fp32, border = 1.0
// ---------------------------------------------------------------------------
__global__ __launch_bounds__(256) void pad_fill(
    const float* __restrict__ phi, const float* __restrict__ bk, const float* __restrict__ bv,
    float* __restrict__ Kp, float* __restrict__ Vp, float* __restrict__ PhiT)
{
    int idx = blockIdx.x * 256 + threadIdx.x;
    const int tot = B_*HP_*HP_;
    if (idx >= tot) return;
    int b  = idx / (HP_*HP_);
    int pp = idx % (HP_*HP_);
    int py = pp / HP_, px = pp % HP_;
    bool interior = (py >= PAD_ && py < H_+PAD_ && px >= PAD_ && px < W_+PAD_);
    if (!interior) {
        size_t base = ((size_t)b*HP_*HP_ + pp) * C_;
        #pragma unroll 8
        for (int c4 = 0; c4 < 32; ++c4) {
            ((float4*)(Kp + base))[c4] = ((const float4*)bk)[c4];
            ((float4*)(Vp + base))[c4] = ((const float4*)bv)[c4];
        }
    }
    size_t pb = ((size_t)b*HP_*HP_ + pp) * M_;
    if (interior) {
        int y = py - PAD_, xx = px - PAD_;
        #pragma unroll
        for (int m = 0; m < M_; ++m)
            PhiT[pb + m] = phi[((size_t)b*M_ + m)*N_ + y*W_ + xx];
    } else {
        #pragma unroll
        for (int m = 0; m < M_; ++m) PhiT[pb + m] = 1.0f;
    }
}

// ---------------------------------------------------------------------------
// Kernel 2: fused Q/K/V projection (fp32 GEMV tiles).
// ---------------------------------------------------------------------------
__global__ __launch_bounds__(256, 3) void qkv_proj(
    const float* __restrict__ x,
    const float* __restrict__ Wq, const float* __restrict__ bq,
    const float* __restrict__ Wk, const float* __restrict__ bk,
    const float* __restrict__ Wv, const float* __restrict__ bv,
    float* __restrict__ Qp, float* __restrict__ Kp, float* __restrict__ Vp)
{
    __shared__ float4 ldsW4[64*32];   // 64 ci rows x 128 co  (32 KB)
    __shared__ float4 ldsX4[128*8];   // [ci][pix] 128 x 32   (16 KB)

    const int t   = threadIdx.x;
    const int blk = blockIdx.x;                 // B_*(N_/32) = 576
    const int b   = blk / (N_/32);
    const int n0  = (blk % (N_/32)) * 32;

    for (int idx = t; idx < 128*32; idx += 256) {
        int pix = idx & 31, ci = idx >> 5;
        ((float*)ldsX4)[ci*32 + pix] = x[((size_t)b*C_ + ci)*N_ + n0 + pix];
    }

    const float* Ws[3] = {Wq, Wk, Wv};
    const float* bs[3] = {bq, bk, bv};

    const int co_g  = t & 31;   // co = co_g*4 .. +3
    const int pix_g = t >> 5;   // pix = pix_g*4 .. +3

    for (int pj = 0; pj < 3; ++pj) {
        float4 bias = *(const float4*)(bs[pj] + co_g*4);
        float4 acc0 = bias, acc1 = bias, acc2 = bias, acc3 = bias;
        for (int half = 0; half < 2; ++half) {
            __syncthreads();
            const float4* wsrc = (const float4*)(Ws[pj] + (size_t)half*64*C_);
            for (int idx = t; idx < 64*32; idx += 256) ldsW4[idx] = wsrc[idx];
            __syncthreads();
            #pragma unroll 8
            for (int ci = 0; ci < 64; ++ci) {
                float4 xv = ldsX4[(half*64 + ci)*8 + pix_g];
                float4 wv = ldsW4[ci*32 + co_g];
                fma4(acc0, xv.x, wv);
                fma4(acc1, xv.y, wv);
                fma4(acc2, xv.z, wv);
                fma4(acc3, xv.w, wv);
            }
        }
        float4 accs[4] = {acc0, acc1, acc2, acc3};
        #pragma unroll
        for (int p = 0; p < 4; ++p) {
            int n = n0 + pix_g*4 + p;
            if (pj == 0) {
                *(float4*)(Qp + ((size_t)b*N_ + n)*C_ + co_g*4) = accs[p];
            } else {
                int y = n / W_, xx = n % W_;
                size_t off = (((size_t)b*HP_ + (y+PAD_))*HP_ + (xx+PAD_))*C_ + co_g*4;
                float* dst = (pj == 1) ? Kp : Vp;
                *(float4*)(dst + off) = accs[p];
            }
        }
    }
}

// ---------------------------------------------------------------------------
// Kernel 3: local attention, 4 threads per (pixel, head).
// Block = (b, head, 8x8 tile); 256 threads = 64 pixels x 4 sub-lanes.
// Sub-lane s owns channels [s*8, s*8+8) and phi dims [s*4, s*4+4).
// logit = scale*qk + gcoef*dsq is linear in both partitions ->
// per-lane combined partial + 2x shfl_xor butterfly gives the full logit.
// K/V halo 14x14 in bf16 LDS, phi halo in fp32 LDS. No spills (l[49]+q8+o8).
// ---------------------------------------------------------------------------
__global__ __launch_bounds__(256, 4) void attn(
    const float* __restrict__ Qp, const float* __restrict__ Kp, const float* __restrict__ Vp,
    const float* __restrict__ PhiT, const float* __restrict__ log_alpha,
    const float* __restrict__ beta, float* __restrict__ AO)
{
    __shared__ uint4  kl[NHALO_*4];   // 196 rows x 4 slots (8 bf16) = 12544 B
    __shared__ uint4  vl[NHALO_*4];   // 12544 B
    __shared__ float4 pl[NHALO_*4];   // 196 rows x 16 fp32 phi     = 12544 B

    const int t  = threadIdx.x;
    const int h  = blockIdx.y;
    const int b  = blockIdx.z;
    const int y0 = ((int)blockIdx.x / (W_/TILE_)) * TILE_;
    const int x0 = ((int)blockIdx.x % (W_/TILE_)) * TILE_;

    // stage halo: K/V -> bf16, phi -> fp32
    for (int idx = t; idx < NHALO_*4; idx += 256) {
        int hp = idx >> 2, sb = idx & 3;
        int hy = hp / HALO_, hx = hp % HALO_;
        size_t rowb = (((size_t)b*HP_ + (y0+hy))*HP_ + (x0+hx));
        size_t gb = rowb*C_ + h*HD_ + sb*8;
        float4 ka = *(const float4*)(Kp + gb);
        float4 kb = *(const float4*)(Kp + gb + 4);
        float4 va = *(const float4*)(Vp + gb);
        float4 vb = *(const float4*)(Vp + gb + 4);
        uint4 ku, vu;
        ku.x = f2bf(ka.x) | (f2bf(ka.y) << 16);
        ku.y = f2bf(ka.z) | (f2bf(ka.w) << 16);
        ku.z = f2bf(kb.x) | (f2bf(kb.y) << 16);
        ku.w = f2bf(kb.z) | (f2bf(kb.w) << 16);
        vu.x = f2bf(va.x) | (f2bf(va.y) << 16);
        vu.y = f2bf(va.z) | (f2bf(va.w) << 16);
        vu.z = f2bf(vb.x) | (f2bf(vb.y) << 16);
        vu.w = f2bf(vb.z) | (f2bf(vb.w) << 16);
        kl[idx] = ku; vl[idx] = vu;
        pl[idx] = *(const float4*)(PhiT + rowb*M_ + sb*4);
    }
    __syncthreads();

    const int s  = t & 3;       // sub-lane: channels s*8.., phi dims s*4..
    const int p  = t >> 2;      // pixel 0..63
    const int qy = p >> 3, qx = p & 7;
    const int n  = (y0+qy)*W_ + (x0+qx);

    float4 q0, q1;
    {
        const float* qptr = Qp + ((size_t)b*N_ + n)*C_ + h*HD_ + s*8;
        q0 = ((const float4*)qptr)[0];
        q1 = ((const float4*)qptr)[1];
    }
    float4 pc = pl[((qy+PAD_)*HALO_ + (qx+PAD_))*4 + s];

    const float alpha = __expf(log_alpha[0]);
    const float scale = 0.17677669529663687f;                 // HD^-0.5 = 1/sqrt(32)
    const float gcoef = -beta[h] * alpha * 0.17677669529663687f; // -beta*alpha/sqrt(2M)

    float l[KW_];
    float mx = -1e30f;
    #pragma unroll
    for (int i = 0; i < WIN_; ++i) {
        #pragma unroll
        for (int j = 0; j < WIN_; ++j) {
            int hp = (qy+i)*HALO_ + (qx+j);
            uint4 kw = kl[(hp<<2) + s];
            float4 acc = make_float4(0.f,0.f,0.f,0.f);
            acc.x = fmaf(q0.x, bf_lo(kw.x), acc.x);
            acc.y = fmaf(q0.y, bf_hi(kw.x), acc.y);
            acc.z = fmaf(q0.z, bf_lo(kw.y), acc.z);
            acc.w = fmaf(q0.w, bf_hi(kw.y), acc.w);
            acc.x = fmaf(q1.x, bf_lo(kw.z), acc.x);
            acc.y = fmaf(q1.y, bf_hi(kw.z), acc.y);
            acc.z = fmaf(q1.z, bf_lo(kw.w), acc.z);
            acc.w = fmaf(q1.w, bf_hi(kw.w), acc.w);
            float pdot = (acc.x + acc.y) + (acc.z + acc.w);

            float4 pv = pl[(hp<<2) + s];
            float d0 = pc.x - pv.x, d1 = pc.y - pv.y;
            float d2 = pc.z - pv.z, d3 = pc.w - pv.w;
            float pdsq = fmaf(d0,d0, fmaf(d1,d1, fmaf(d2,d2, d3*d3)));

            float part = fmaf(pdot, scale, gcoef*pdsq);
            part += __shfl_xor(part, 1);
            part += __shfl_xor(part, 2);    // lanes 4p..4p+3 all hold full logit
            l[i*WIN_+j] = part;
            mx = fmaxf(mx, part);
        }
    }
    float ssum = 0.f;
    #pragma unroll
    for (int kk = 0; kk < KW_; ++kk) { float e = __expf(l[kk]-mx); l[kk] = e; ssum += e; }
    float inv = 1.0f / ssum;

    float4 o0 = make_float4(0.f,0.f,0.f,0.f);
    float4 o1 = make_float4(0.f,0.f,0.f,0.f);
    #pragma unroll
    for (int i = 0; i < WIN_; ++i) {
        #pragma unroll
        for (int j = 0; j < WIN_; ++j) {
            int hp = (qy+i)*HALO_ + (qx+j);
            float w = l[i*WIN_+j];
            uint4 vw = vl[(hp<<2) + s];
            o0.x = fmaf(w, bf_lo(vw.x), o0.x);
            o0.y = fmaf(w, bf_hi(vw.x), o0.y);
            o0.z = fmaf(w, bf_lo(vw.y), o0.z);
            o0.w = fmaf(w, bf_hi(vw.y), o0.w);
            o1.x = fmaf(w, bf_lo(vw.z), o1.x);
            o1.y = fmaf(w, bf_hi(vw.z), o1.y);
            o1.z = fmaf(w, bf_lo(vw.w), o1.z);
            o1.w = fmaf(w, bf_hi(vw.w), o1.w);
        }
    }
    float* aop = AO + ((size_t)b*N_ + n)*C_ + h*HD_ + s*8;
    o0.x *= inv; o0.y *= inv; o0.z *= inv; o0.w *= inv;
    o1.x *= inv; o1.y *= inv; o1.z *= inv; o1.w *= inv;
    ((float4*)aop)[0] = o0;
    ((float4*)aop)[1] = o1;
}

// ---------------------------------------------------------------------------
// Kernel 4: output projection.
// ---------------------------------------------------------------------------
__global__ __launch_bounds__(256, 4) void out_proj(
    const float* __restrict__ AO, const float* __restrict__ Wo,
    const float* __restrict__ bo, float* __restrict__ out)
{
    __shared__ float4 aos[64*32];   // 32 KB
    const int t   = threadIdx.x;
    const int blk = blockIdx.x;                 // B_*(N_/64) = 288
    const int b   = blk / (N_/64);
    const int n0  = (blk % (N_/64)) * 64;

    for (int idx = t; idx < 64*32; idx += 256) {
        int nl = idx >> 5, c4 = idx & 31;
        aos[nl*32 + (c4 ^ (nl & 31))] =
            ((const float4*)(AO + ((size_t)b*N_ + n0 + nl)*C_))[c4];
    }
    __syncthreads();

    const int nl = t & 63, cg = t >> 6;
    const int n  = n0 + nl;
    #pragma unroll
    for (int c8 = 0; c8 < 8; ++c8) {
        int co = cg*32 + c8*4;
        float4 acc = *(const float4*)(bo + co);
        #pragma unroll 8
        for (int c4 = 0; c4 < 32; ++c4) {
            float4 xv = aos[nl*32 + (c4 ^ (nl & 31))];
            float4 w0 = *(const float4*)(Wo + (size_t)(c4*4+0)*C_ + co);
            float4 w1 = *(const float4*)(Wo + (size_t)(c4*4+1)*C_ + co);
            float4 w2 = *(const float4*)(Wo + (size_t)(c4*4+2)*C_ + co);
            float4 w3 = *(const float4*)(Wo + (size_t)(c4*4+3)*C_ + co);
            fma4(acc, xv.x, w0);
            fma4(acc, xv.y, w1);
            fma4(acc, xv.z, w2);
            fma4(acc, xv.w, w3);
        }
        out[((size_t)b*C_ + co+0)*N_ + n] = acc.x;
        out[((size_t)b*C_ + co+1)*N_ + n] = acc.y;
        out[((size_t)b*C_ + co+2)*N_ + n] = acc.z;
        out[((size_t)b*C_ + co+3)*N_ + n] = acc.w;
    }
}

// ---------------------------------------------------------------------------
extern "C" void kernel_launch(void* const* d_in, const int* in_sizes, int n_in,
                              void* d_out, int out_size, void* d_ws, size_t ws_size,
                              hipStream_t stream)
{
    const float* x    = (const float*)d_in[0];
    const float* phi  = (const float*)d_in[1];
    const float* Wq   = (const float*)d_in[2];
    const float* bq   = (const float*)d_in[3];
    const float* Wk   = (const float*)d_in[4];
    const float* bk   = (const float*)d_in[5];
    const float* Wv   = (const float*)d_in[6];
    const float* bv   = (const float*)d_in[7];
    const float* Wo   = (const float*)d_in[8];
    const float* bo   = (const float*)d_in[9];
    const float* la   = (const float*)d_in[10];
    const float* beta = (const float*)d_in[11];
    float* out = (float*)d_out;

    // workspace layout (floats). AO aliases Qp: each attn thread fully reads
    // its q slice into registers before writing the identical AO slice.
    float* ws   = (float*)d_ws;
    float* Qp   = ws;                                   // B*N*C      = 2,359,296
    float* Kp   = Qp + (size_t)B_*N_*C_;                // B*102^2*C  = 2,663,424
    float* Vp   = Kp + (size_t)B_*HP_*HP_*C_;           // B*102^2*C  = 2,663,424
    float* PhiT = Vp + (size_t)B_*HP_*HP_*C_;           // B*102^2*M  =   332,928
    float* AO   = Qp;                                   // aliased

    pad_fill<<<dim3((B_*HP_*HP_ + 255)/256), dim3(256), 0, stream>>>(phi, bk, bv, Kp, Vp, PhiT);
    qkv_proj<<<dim3(B_*(N_/32)), dim3(256), 0, stream>>>(x, Wq, bq, Wk, bk, Wv, bv, Qp, Kp, Vp);
    attn<<<dim3((H_/TILE_)*(W_/TILE_), HEADS_, B_), dim3(256), 0, stream>>>(Qp, Kp, Vp, PhiT, la, beta, AO);
    out_proj<<<dim3(B_*(N_/64)), dim3(256), 0, stream>>>(AO, Wo, bo, out);
}